// Round 5
// baseline (325.812 us; speedup 1.0000x reference)
//
#include <hip/hip_runtime.h>
#include <math.h>

#define NB 64
#define NC 512
#define NHW 4096
#define NHID 32
#define NPLANES (NB * NC)          // 32768 planes of 4096 floats

typedef float f32x4 __attribute__((ext_vector_type(4)));

// ---------------- Kernel 1: global average pool ----------------
// Wave-per-plane: each 64-lane wave reduces one 16 KiB plane entirely in
// registers (16 float4/lane), 6-shfl butterfly, no LDS, no barrier.
__global__ __launch_bounds__(256) void pool_kernel(const float* __restrict__ x,
                                                   float* __restrict__ y) {
    const int wid   = threadIdx.x >> 6;
    const int lane  = threadIdx.x & 63;
    const int plane = blockIdx.x * 4 + wid;
    const f32x4* __restrict__ xin =
        reinterpret_cast<const f32x4*>(x + (size_t)plane * NHW);

    float s = 0.f;
#pragma unroll
    for (int i = 0; i < 16; ++i) {
        f32x4 v = xin[lane + i * 64];                // 1 KiB contiguous per wave-iter
        s += v.x + v.y + v.z + v.w;
    }
#pragma unroll
    for (int o = 32; o; o >>= 1) s += __shfl_down(s, o, 64);
    if (lane == 0) y[plane] = s * (1.0f / NHW);
}

// ---------------- Kernel 2: routed 2-layer MLP -> sigmoid gate ----------------
__global__ __launch_bounds__(256) void gate_kernel(const float* __restrict__ y,
                                                   const int* __restrict__ dataset,
                                                   const float* __restrict__ W1,
                                                   const float* __restrict__ W2,
                                                   float* __restrict__ gate) {
    const int b = blockIdx.x;
    const int tid = threadIdx.x;

    __shared__ float ys[NC];
    __shared__ float hs[NHID];

    ys[tid]       = y[b * NC + tid];
    ys[tid + 256] = y[b * NC + tid + 256];
    const int e = dataset[b];
    __syncthreads();

    const int hid = tid >> 3;
    const int j   = tid & 7;
    const float* __restrict__ w1row = W1 + ((size_t)e * NHID + hid) * NC;
    float acc = 0.f;
    for (int c = j; c < NC; c += 8) acc += ys[c] * w1row[c];
#pragma unroll
    for (int o = 4; o; o >>= 1) acc += __shfl_down(acc, o, 8);
    if (j == 0) hs[hid] = fmaxf(acc, 0.f);
    __syncthreads();

    const float* __restrict__ w2base = W2 + (size_t)e * NC * NHID;
#pragma unroll
    for (int k = 0; k < 2; ++k) {
        const int c = tid + k * 256;
        const float* __restrict__ w2row = w2base + c * NHID;
        float z = 0.f;
#pragma unroll
        for (int hh = 0; hh < NHID; ++hh) z += hs[hh] * w2row[hh];
        gate[b * NC + c] = 1.0f / (1.0f + expf(-z));
    }
}

// ---------------- Kernel 3: out = x * gate[b,c] ----------------
// m13-copy-style: ascending, plain float4 loads AND plain stores (nt stores
// measured null-to-negative; L3 retention gives nothing on this part).
// Block = 2 planes so the gate factors are wave-uniform scalar loads.
__global__ __launch_bounds__(256) void scale_kernel(const float* __restrict__ x,
                                                    const float* __restrict__ gate,
                                                    float* __restrict__ out) {
    const int pair = blockIdx.x;                         // ascending
    const int p0 = pair * 2;
    const float g0 = gate[p0];
    const float g1 = gate[p0 + 1];
    const size_t base = (size_t)pair * 2048;             // float4 units
    const f32x4* __restrict__ xin = reinterpret_cast<const f32x4*>(x);
    f32x4* __restrict__ o4 = reinterpret_cast<f32x4*>(out);
    const int t = threadIdx.x;

#pragma unroll
    for (int k = 0; k < 4; ++k) {
        const size_t i = base + (size_t)k * 256 + t;
        f32x4 v = xin[i];
        v *= g0;
        o4[i] = v;
    }
#pragma unroll
    for (int k = 0; k < 4; ++k) {
        const size_t i = base + 1024 + (size_t)k * 256 + t;
        f32x4 v = xin[i];
        v *= g1;
        o4[i] = v;
    }
}

extern "C" void kernel_launch(void* const* d_in, const int* in_sizes, int n_in,
                              void* d_out, int out_size, void* d_ws, size_t ws_size,
                              hipStream_t stream) {
    const float* x       = (const float*)d_in[0];
    const int*   dataset = (const int*)d_in[1];
    const float* W1      = (const float*)d_in[2];
    const float* W2      = (const float*)d_in[3];
    float* out = (float*)d_out;

    float* y    = (float*)d_ws;          // NB*NC floats
    float* gate = y + NB * NC;           // NB*NC floats

    pool_kernel<<<NPLANES / 4, 256, 0, stream>>>(x, y);
    gate_kernel<<<NB, 256, 0, stream>>>(y, dataset, W1, W2, gate);
    scale_kernel<<<NPLANES / 2, 256, 0, stream>>>(x, gate, out);
}

// Round 6
// 289.121 us; speedup vs baseline: 1.1269x; 1.1269x over previous
//
#include <hip/hip_runtime.h>
#include <math.h>

#define NB 64
#define NC 512
#define NHW 4096
#define NHID 32
#define NPLANES (NB * NC)          // 32768 planes of 4096 floats

typedef float f32x4 __attribute__((ext_vector_type(4)));

// ---------------- Kernel 1: global average pool ----------------
// Wave-per-plane: each 64-lane wave reduces one 16 KiB plane entirely in
// registers (16 float4/lane), 6-shfl butterfly, no LDS, no barrier.
// Measured at ~6.3 TB/s (read ceiling) — unchanged.
__global__ __launch_bounds__(256) void pool_kernel(const float* __restrict__ x,
                                                   float* __restrict__ y) {
    const int wid   = threadIdx.x >> 6;
    const int lane  = threadIdx.x & 63;
    const int plane = blockIdx.x * 4 + wid;
    const f32x4* __restrict__ xin =
        reinterpret_cast<const f32x4*>(x + (size_t)plane * NHW);

    float s = 0.f;
#pragma unroll
    for (int i = 0; i < 16; ++i) {
        f32x4 v = xin[lane + i * 64];
        s += v.x + v.y + v.z + v.w;
    }
#pragma unroll
    for (int o = 32; o; o >>= 1) s += __shfl_down(s, o, 64);
    if (lane == 0) y[plane] = s * (1.0f / NHW);
}

// ---------------- Kernel 2: routed 2-layer MLP -> sigmoid gate ----------------
__global__ __launch_bounds__(256) void gate_kernel(const float* __restrict__ y,
                                                   const int* __restrict__ dataset,
                                                   const float* __restrict__ W1,
                                                   const float* __restrict__ W2,
                                                   float* __restrict__ gate) {
    const int b = blockIdx.x;
    const int tid = threadIdx.x;

    __shared__ float ys[NC];
    __shared__ float hs[NHID];

    ys[tid]       = y[b * NC + tid];
    ys[tid + 256] = y[b * NC + tid + 256];
    const int e = dataset[b];
    __syncthreads();

    const int hid = tid >> 3;
    const int j   = tid & 7;
    const float* __restrict__ w1row = W1 + ((size_t)e * NHID + hid) * NC;
    float acc = 0.f;
    for (int c = j; c < NC; c += 8) acc += ys[c] * w1row[c];
#pragma unroll
    for (int o = 4; o; o >>= 1) acc += __shfl_down(acc, o, 8);
    if (j == 0) hs[hid] = fmaxf(acc, 0.f);
    __syncthreads();

    const float* __restrict__ w2base = W2 + (size_t)e * NC * NHID;
#pragma unroll
    for (int k = 0; k < 2; ++k) {
        const int c = tid + k * 256;
        const float* __restrict__ w2row = w2base + c * NHID;
        float z = 0.f;
#pragma unroll
        for (int hh = 0; hh < NHID; ++hh) z += hs[hh] * w2row[hh];
        gate[b * NC + c] = 1.0f / (1.0f + expf(-z));
    }
}

// ---------------- Kernel 3: out = x * gate[b,c] ----------------
// Best-known config (R2): descending order + non-temporal stores. New this
// round: 4 planes per block; each thread issues ALL 16 float4 loads first
// (deep MLP, one waitcnt), then 16 muls + 16 nt stores (long same-direction
// bursts at the HBM controller).
__global__ __launch_bounds__(256) void scale_kernel(const float* __restrict__ x,
                                                    const float* __restrict__ gate,
                                                    float* __restrict__ out) {
    const int blk = gridDim.x - 1 - blockIdx.x;          // descending
    const int p0 = blk * 4;
    const size_t base = (size_t)blk * 4096;              // float4 units (4 planes)
    const f32x4* __restrict__ xin = reinterpret_cast<const f32x4*>(x);
    f32x4* __restrict__ o4 = reinterpret_cast<f32x4*>(out);
    const int t = threadIdx.x;

    float g[4];
#pragma unroll
    for (int q = 0; q < 4; ++q) g[q] = gate[p0 + q];

    f32x4 v[16];
#pragma unroll
    for (int q = 0; q < 4; ++q)
#pragma unroll
        for (int k = 0; k < 4; ++k)
            v[q * 4 + k] = xin[base + (size_t)q * 1024 + k * 256 + t];

#pragma unroll
    for (int q = 0; q < 4; ++q)
#pragma unroll
        for (int k = 0; k < 4; ++k) {
            f32x4 w = v[q * 4 + k] * g[q];
            __builtin_nontemporal_store(w, &o4[base + (size_t)q * 1024 + k * 256 + t]);
        }
}

extern "C" void kernel_launch(void* const* d_in, const int* in_sizes, int n_in,
                              void* d_out, int out_size, void* d_ws, size_t ws_size,
                              hipStream_t stream) {
    const float* x       = (const float*)d_in[0];
    const int*   dataset = (const int*)d_in[1];
    const float* W1      = (const float*)d_in[2];
    const float* W2      = (const float*)d_in[3];
    float* out = (float*)d_out;

    float* y    = (float*)d_ws;          // NB*NC floats
    float* gate = y + NB * NC;           // NB*NC floats

    pool_kernel<<<NPLANES / 4, 256, 0, stream>>>(x, y);
    gate_kernel<<<NB, 256, 0, stream>>>(y, dataset, W1, W2, gate);
    scale_kernel<<<NPLANES / 4, 256, 0, stream>>>(x, gate, out);
}